// Round 2
// baseline (510.323 us; speedup 1.0000x reference)
//
#include <hip/hip_runtime.h>
#include <hip/hip_bf16.h>

typedef __bf16 bf16x8 __attribute__((ext_vector_type(8)));
typedef float f32x4 __attribute__((ext_vector_type(4)));
typedef unsigned int uint4v __attribute__((ext_vector_type(4)));
typedef unsigned short u16;

__device__ __forceinline__ u16 f2bf(float f) {
  __hip_bfloat16 h = __float2bfloat16(f);  // RNE
  u16 u;
  __builtin_memcpy(&u, &h, 2);
  return u;
}

// ---------------- prep: weight transform (f32->bf16) + BN fold ----------------
// WT[tap][co][cin], co 0..63 = branch a, 64..127 = branch b. cin contiguous.
__global__ void prep_kernel(const float* __restrict__ cwA, const float* __restrict__ cbA,
                            const float* __restrict__ cwB, const float* __restrict__ cbB,
                            const float* gA, const float* beA, const float* mA, const float* vA,
                            const float* gB, const float* beB, const float* mB, const float* vB,
                            const float* abA, const float* abB,
                            const float* agA, const float* abeA, const float* amA, const float* avA,
                            const float* agB, const float* abeB, const float* amB, const float* avB,
                            u16* __restrict__ wt, float* __restrict__ scale,
                            float* __restrict__ shift, float* __restrict__ attc) {
  int g = blockIdx.x * 256 + threadIdx.x;
  if (g < 147456) {
    int cin = g & 127, co = (g >> 7) & 127, tap = g >> 14;
    float v = (co < 64) ? cwA[(co * 128 + cin) * 9 + tap]
                        : cwB[((co - 64) * 128 + cin) * 9 + tap];
    wt[g] = f2bf(v);
  }
  if (g < 128) {
    bool a = g < 64;
    int c = a ? g : g - 64;
    float gam = a ? gA[c] : gB[c];
    float var = a ? vA[c] : vB[c];
    float mea = a ? mA[c] : mB[c];
    float bet = a ? beA[c] : beB[c];
    float bia = a ? cbA[c] : cbB[c];
    float sc = gam / sqrtf(var + 1e-3f);  // EPS_BR
    scale[g] = sc;
    shift[g] = (bia - mea) * sc + bet;
  }
  if (g == 0) {
    float scA = agA[0] / sqrtf(avA[0] + 1e-5f);  // EPS_ATT
    float scB = agB[0] / sqrtf(avB[0] + 1e-5f);
    attc[0] = scA;
    attc[1] = (abA[0] - amA[0]) * scA + abeA[0];
    attc[2] = scB;
    attc[3] = (abB[0] - amB[0]) * scB + abeB[0];
  }
}

// ---------------- conv: 3x3, Cin=128 -> Cout=128, fused BN + fused 1x1 att ----------------
// block = (b,h): 1 row x 256 cols x 128 co. LDS x tile [3 rows][260 cols][cin 32 pad 36] (bf16).
#define LPAD 36
__global__ __launch_bounds__(256, 2) void conv_kernel(
    const float* __restrict__ x, const u16* __restrict__ wt,
    const float* __restrict__ scale, const float* __restrict__ shift,
    const float* __restrict__ attc, const float* __restrict__ wA66,
    const float* __restrict__ wB66, float* __restrict__ f,
    float* __restrict__ atta, float* __restrict__ attb) {
  __shared__ u16 xs[3 * 260 * LPAD];
  const int tid = threadIdx.x;
  const int bid = blockIdx.x;
  // XCD-aware swizzle: consecutive-h blocks land on the same XCD (bid%8 heuristic)
  const int h = (bid & 7) * 32 + ((bid >> 3) & 31);
  const int b = bid >> 8;
  const int l15 = tid & 15, quad = (tid >> 4) & 3, wave = tid >> 6;
  const int mbase = (wave >> 1) * 64;  // waves 0,1 -> co 0..63 (a); 2,3 -> 64..127 (b)
  const int nbase = (wave & 1) * 128;  // waves 0,2 -> cols 0..127; 1,3 -> 128..255

  f32x4 acc[4][8];
  const f32x4 z = {0.f, 0.f, 0.f, 0.f};
#pragma unroll
  for (int i = 0; i < 4; ++i)
#pragma unroll
    for (int j = 0; j < 8; ++j) acc[i][j] = z;

  const u16* wbase = wt + (mbase + l15) * 128 + quad * 8;
  const long xb = (long)b * (128 * 65536);
  bf16x8 aNxt[4];

  for (int q = 0; q < 4; ++q) {  // cin chunks of 32
    {  // prefetch A fragments for tap 0 of this chunk (overlaps staging)
      const u16* p = wbase + q * 32;
#pragma unroll
      for (int mt = 0; mt < 4; ++mt)
        aNxt[mt] = *reinterpret_cast<const bf16x8*>(p + mt * 2048);
    }
    __syncthreads();
    // stage x[cin q*32..+32)[h-1..h+1][w0-2..w0+257] with zero pad, f32 -> bf16
    for (int i = tid; i < 12480; i += 256) {  // 130 col-pairs * 32 cin * 3 rows
      int p = i % 130;
      int rest = i / 130;
      int c = rest & 31, r = rest >> 5;
      int w = p * 2 - 2;
      int hh = h + r - 1;
      float2 v = make_float2(0.f, 0.f);
      if ((unsigned)hh < 256u && (unsigned)w < 256u)
        v = *reinterpret_cast<const float2*>(x + xb + (long)(q * 32 + c) * 65536 + hh * 256 + w);
      int dst = (r * 260 + p * 2) * LPAD + c;
      xs[dst] = f2bf(v.x);
      xs[dst + LPAD] = f2bf(v.y);
    }
    __syncthreads();
#pragma unroll 1
    for (int tap = 0; tap < 9; ++tap) {
      bf16x8 aCur[4];
#pragma unroll
      for (int mt = 0; mt < 4; ++mt) aCur[mt] = aNxt[mt];
      if (tap < 8) {  // prefetch next tap's A
        const u16* p = wbase + q * 32 + (tap + 1) * 16384;
#pragma unroll
        for (int mt = 0; mt < 4; ++mt)
          aNxt[mt] = *reinterpret_cast<const bf16x8*>(p + mt * 2048);
      }
      const int ky = tap / 3, kx = tap - ky * 3;
      bf16x8 bb[8];
#pragma unroll
      for (int nt = 0; nt < 8; ++nt) {
        int col = nbase + nt * 16 + l15 + kx + 1;  // LDS col 0 == w=-2
        const u16* sp = &xs[(ky * 260 + col) * LPAD + quad * 8];
        uint2 lo = *reinterpret_cast<const uint2*>(sp);
        uint2 hi = *reinterpret_cast<const uint2*>(sp + 4);
        uint4v u;
        u[0] = lo.x; u[1] = lo.y; u[2] = hi.x; u[3] = hi.y;
        bb[nt] = __builtin_bit_cast(bf16x8, u);
      }
#pragma unroll
      for (int mt = 0; mt < 4; ++mt)
#pragma unroll
        for (int nt = 0; nt < 8; ++nt)
          acc[mt][nt] =
              __builtin_amdgcn_mfma_f32_16x16x32_bf16(aCur[mt], bb[nt], acc[mt][nt], 0, 0, 0);
    }
  }
  // epilogue: BN fold, write f32 f (into d_out), accumulate 1x1 att dot
  const bool brA = (wave < 2);
  const float* wsel = brA ? wA66 : wB66;
  const long ob = (long)b * (128 * 65536) + h * 256;
  float pa[8];
#pragma unroll
  for (int nt = 0; nt < 8; ++nt) pa[nt] = 0.f;
#pragma unroll
  for (int mt = 0; mt < 4; ++mt) {
    int cob = mbase + mt * 16 + quad * 4;
    f32x4 scl = *reinterpret_cast<const f32x4*>(scale + cob);
    f32x4 shf = *reinterpret_cast<const f32x4*>(shift + cob);
    float wv[4];
#pragma unroll
    for (int e = 0; e < 4; ++e) wv[e] = wsel[mt * 16 + quad * 4 + e];
#pragma unroll
    for (int nt = 0; nt < 8; ++nt) {
      int wo = nbase + nt * 16 + l15;
#pragma unroll
      for (int e = 0; e < 4; ++e) {
        float v = acc[mt][nt][e] * scl[e] + shf[e];
        f[ob + (long)(cob + e) * 65536 + wo] = v;
        pa[nt] += wv[e] * v;
      }
    }
  }
#pragma unroll
  for (int nt = 0; nt < 8; ++nt) {
    pa[nt] += __shfl_xor(pa[nt], 16);
    pa[nt] += __shfl_xor(pa[nt], 32);
  }
  // lanes (quad,l15) publish cols for nt = 2*quad, 2*quad+1
  float w64 = wsel[64], w65 = wsel[65];
  float sc = brA ? attc[0] : attc[2];
  float sh = brA ? attc[1] : attc[3];
  float ghv = fabsf((float)h - 127.5f) * (1.f / 128.f);
  float* ap = brA ? atta : attb;
#pragma unroll
  for (int j = 0; j < 2; ++j) {
    int nt = quad * 2 + j;
    int col = nbase + nt * 16 + l15;
    float gwv = fabsf((float)col - 127.5f) * (1.f / 128.f);
    ap[b * 65536 + h * 256 + col] = (pa[nt] + w64 * ghv + w65 * gwv) * sc + sh;
  }
}

// ---------------- map: 3x3 conv over [att, gh, gw, pr] + sigmoid, in-place mul ----------------
__global__ void map_kernel(const float* __restrict__ atta, const float* __restrict__ attb,
                           const float* __restrict__ awA, const float* __restrict__ awB,
                           const float* __restrict__ s1p, const float* __restrict__ s2p,
                           float* __restrict__ out) {
  __shared__ float wsh[72];
  __shared__ float la[3 * 258], lb[3 * 258];
  int tid = threadIdx.x;
  int bid = blockIdx.x;
  int h = bid & 255, b = bid >> 8;
  if (tid < 36) wsh[tid] = awA[tid];
  else if (tid < 72) wsh[tid] = awB[tid - 36];
  for (int i = tid; i < 774; i += 256) {  // 3 rows x 258 cols (w=-1..256), zero pad
    int r = i / 258, cc = i - r * 258;
    int ww = cc - 1, hh = h + r - 1;
    float va = 0.f, vb = 0.f;
    if ((unsigned)hh < 256u && (unsigned)ww < 256u) {
      int o = b * 65536 + hh * 256 + ww;
      va = atta[o];
      vb = attb[o];
    }
    la[r * 258 + cc] = va;
    lb[r * 258 + cc] = vb;
  }
  __syncthreads();
  const float r2 = sqrtf(2.f);
  const float rmx = r2 * (127.5f / 128.f);
  const float rmn = r2 * (0.5f / 128.f);
  const float Kc = 2.f / (rmx - rmn);
  const float C0 = 1.f - rmx * Kc;
  int w = tid;
  float suma = 0.f, sumb = 0.f;
#pragma unroll
  for (int ky = 0; ky < 3; ++ky) {
    int hh = h + ky - 1;
    if ((unsigned)hh < 256u) {
      float ghv = fabsf((float)hh - 127.5f) * (1.f / 128.f);
#pragma unroll
      for (int kx = 0; kx < 3; ++kx) {
        int ww = w + kx - 1;
        if ((unsigned)ww < 256u) {  // zero padding zeroes ALL 4 channels
          int t = ky * 3 + kx;
          float gwv = fabsf((float)ww - 127.5f) * (1.f / 128.f);
          float prv = Kc * sqrtf(ghv * ghv + gwv * gwv) + C0;
          suma += wsh[t] * la[ky * 258 + ww + 1] + wsh[9 + t] * ghv + wsh[18 + t] * gwv +
                  wsh[27 + t] * prv;
          sumb += wsh[36 + t] * lb[ky * 258 + ww + 1] + wsh[45 + t] * ghv + wsh[54 + t] * gwv +
                  wsh[63 + t] * prv;
        }
      }
    }
  }
  float mfa = s1p[0] / (1.f + expf(-suma));
  float mfb = s2p[0] / (1.f + expf(-sumb));
  long base = (long)b * (128 * 65536) + h * 256 + w;
#pragma unroll 4
  for (int co = 0; co < 64; ++co) {
    long o = base + (long)co * 65536;
    out[o] = out[o] * mfa;
  }
#pragma unroll 4
  for (int co = 64; co < 128; ++co) {
    long o = base + (long)co * 65536;
    out[o] = out[o] * mfb;
  }
}

extern "C" void kernel_launch(void* const* d_in, const int* in_sizes, int n_in,
                              void* d_out, int out_size, void* d_ws, size_t ws_size,
                              hipStream_t stream) {
  const float* x = (const float*)d_in[0];
  u16* wt = (u16*)d_ws;                                     // 294912 B
  float* scale = (float*)((char*)d_ws + 294912);            // 512 B
  float* shift = (float*)((char*)d_ws + 295424);            // 512 B
  float* attc = (float*)((char*)d_ws + 295936);             // 64 B
  float* atta = (float*)((char*)d_ws + 296000);             // 1 MiB
  float* attb = (float*)((char*)d_ws + 296000 + 1048576);   // 1 MiB
  float* out = (float*)d_out;

  prep_kernel<<<576, 256, 0, stream>>>(
      (const float*)d_in[1], (const float*)d_in[2], (const float*)d_in[3], (const float*)d_in[4],
      (const float*)d_in[5], (const float*)d_in[6], (const float*)d_in[7], (const float*)d_in[8],
      (const float*)d_in[9], (const float*)d_in[10], (const float*)d_in[11], (const float*)d_in[12],
      (const float*)d_in[14], (const float*)d_in[16],
      (const float*)d_in[17], (const float*)d_in[18], (const float*)d_in[19], (const float*)d_in[20],
      (const float*)d_in[21], (const float*)d_in[22], (const float*)d_in[23], (const float*)d_in[24],
      wt, scale, shift, attc);
  conv_kernel<<<1024, 256, 0, stream>>>(x, wt, scale, shift, attc,
                                        (const float*)d_in[13], (const float*)d_in[15],
                                        out, atta, attb);
  map_kernel<<<1024, 256, 0, stream>>>(atta, attb, (const float*)d_in[25], (const float*)d_in[26],
                                       (const float*)d_in[27], (const float*)d_in[28], out);
}

// Round 3
// 401.308 us; speedup vs baseline: 1.2716x; 1.2716x over previous
//
#include <hip/hip_runtime.h>
#include <hip/hip_bf16.h>

typedef __bf16 bf16x8 __attribute__((ext_vector_type(8)));
typedef float f32x4 __attribute__((ext_vector_type(4)));
typedef unsigned int uint4v __attribute__((ext_vector_type(4)));
typedef unsigned short u16;

__device__ __forceinline__ u16 f2bf(float f) {
  __hip_bfloat16 h = __float2bfloat16(f);  // RNE
  u16 u;
  __builtin_memcpy(&u, &h, 2);
  return u;
}

__device__ __forceinline__ void dma16(const u16* src, u16* ldsDst) {
  __builtin_amdgcn_global_load_lds(
      (const __attribute__((address_space(1))) void*)src,
      (__attribute__((address_space(3))) void*)ldsDst, 16, 0, 0);
}

// ---------------- xpose: x NCHW f32 -> xT NHWC bf16 ----------------
__global__ void xpose_kernel(const float* __restrict__ x, u16* __restrict__ xT) {
  __shared__ u16 tile[64 * 132];
  const int tid = threadIdx.x;
  const int bid = blockIdx.x;
  const int wt_i = bid & 3, h = (bid >> 2) & 255, b = bid >> 10;
  const int w = tid & 63, cg = tid >> 6;
  const long xb = (long)b * (128 * 65536) + h * 256 + wt_i * 64 + w;
#pragma unroll 8
  for (int i = 0; i < 32; ++i) {
    int c = cg + i * 4;
    float v = x[xb + (long)c * 65536];
    tile[w * 132 + c] = f2bf(v);
  }
  __syncthreads();
  const int cq = tid & 31;
  const long ob = ((long)(b * 256 + h) * 256 + wt_i * 64) * 128;
#pragma unroll
  for (int j = 0; j < 8; ++j) {
    int wl = j * 8 + (tid >> 5);
    uint2 v = *reinterpret_cast<const uint2*>(&tile[wl * 132 + cq * 4]);
    *reinterpret_cast<uint2*>(xT + ob + wl * 128 + cq * 4) = v;
  }
}

// ---------------- prep (fast): WT2[q*9+tap][co][cin8 chunk] + BN fold ----------------
__global__ void prep_kernel(const float* __restrict__ cwA, const float* __restrict__ cbA,
                            const float* __restrict__ cwB, const float* __restrict__ cbB,
                            const float* gA, const float* beA, const float* mA, const float* vA,
                            const float* gB, const float* beB, const float* mB, const float* vB,
                            const float* abA, const float* abB,
                            const float* agA, const float* abeA, const float* amA, const float* avA,
                            const float* agB, const float* abeB, const float* amB, const float* avB,
                            u16* __restrict__ wt, float* __restrict__ scale,
                            float* __restrict__ shift, float* __restrict__ attc) {
  int g = blockIdx.x * 256 + threadIdx.x;
  if (g < 147456) {
    int p = g >> 12, co = (g >> 5) & 127, cl = g & 31;
    int q = p / 9, tap = p - q * 9;
    int cin = q * 32 + cl;
    float v = (co < 64) ? cwA[(co * 128 + cin) * 9 + tap]
                        : cwB[((co - 64) * 128 + cin) * 9 + tap];
    wt[g] = f2bf(v);
  }
  if (g < 128) {
    bool a = g < 64;
    int c = a ? g : g - 64;
    float gam = a ? gA[c] : gB[c];
    float var = a ? vA[c] : vB[c];
    float mea = a ? mA[c] : mB[c];
    float bet = a ? beA[c] : beB[c];
    float bia = a ? cbA[c] : cbB[c];
    float sc = gam / sqrtf(var + 1e-3f);  // EPS_BR
    scale[g] = sc;
    shift[g] = (bia - mea) * sc + bet;
  }
  if (g == 0) {
    float scA = agA[0] / sqrtf(avA[0] + 1e-5f);  // EPS_ATT
    float scB = agB[0] / sqrtf(avB[0] + 1e-5f);
    attc[0] = scA;
    attc[1] = (abA[0] - amA[0]) * scA + abeA[0];
    attc[2] = scB;
    attc[3] = (abB[0] - amB[0]) * scB + abeB[0];
  }
}

// ---------------- conv (fast): DMA-staged LDS, b128 fragment reads ----------------
// LDS xs[row 0..2][col 0..259][cin 0..31] u16, cin contiguous (64 B per (row,col)).
__global__ __launch_bounds__(256, 2) void conv_kernel(
    const u16* __restrict__ xT, const u16* __restrict__ wt2,
    const float* __restrict__ scale, const float* __restrict__ shift,
    const float* __restrict__ attc, const float* __restrict__ wA66,
    const float* __restrict__ wB66, float* __restrict__ f,
    float* __restrict__ atta, float* __restrict__ attb) {
  __shared__ u16 xs[3 * 260 * 32];
  const int tid = threadIdx.x;
  const int bid = blockIdx.x;
  const int h = (bid & 7) * 32 + ((bid >> 3) & 31);  // XCD-local h grouping
  const int b = bid >> 8;
  const int l15 = tid & 15, quad = (tid >> 4) & 3, wave = tid >> 6, ln = tid & 63;
  const int mbase = (wave >> 1) * 64;
  const int nbase = (wave & 1) * 128;

  // zero halo once: pad cols {0,1,258,259} x 3 rows; OOB rows for h edges.
  unsigned* xs32 = (unsigned*)xs;
  for (int i = tid; i < 192; i += 256) {
    int r = i >> 6, ci = (i >> 4) & 3, dw = i & 15;
    int col = (ci < 2) ? ci : 256 + ci;
    xs32[(r * 260 + col) * 16 + dw] = 0u;
  }
  if (h == 0)
    for (int i = tid; i < 4160; i += 256) xs32[i] = 0u;
  if (h == 255)
    for (int i = tid; i < 4160; i += 256) xs32[8320 + i] = 0u;

  f32x4 acc[4][8];
  const f32x4 z = {0.f, 0.f, 0.f, 0.f};
#pragma unroll
  for (int i = 0; i < 4; ++i)
#pragma unroll
    for (int j = 0; j < 8; ++j) acc[i][j] = z;

  const int aoff = (mbase + l15) * 32 + quad * 8;
  const int ldsLaneOff = (nbase + l15) * 32 + quad * 8;
  const long xtb = (long)b * (256 * 256 * 128);
  bf16x8 aNxt[4];
  {
    const u16* p = wt2 + aoff;
#pragma unroll
    for (int mt = 0; mt < 4; ++mt) aNxt[mt] = *reinterpret_cast<const bf16x8*>(p + mt * 512);
  }

  for (int q = 0; q < 4; ++q) {
    __syncthreads();  // previous q's reads done / halo visible
#pragma unroll 1
    for (int i = 0; i < 12; ++i) {
      int chunk = wave * 12 + i;
      int r = chunk >> 4, g = chunk & 15;
      int hh = h + r - 1;
      if ((unsigned)hh < 256u) {
        const u16* src = xT + xtb + ((long)(hh * 256 + g * 16 + (ln >> 2)) * 128 + q * 32 + (ln & 3) * 8);
        dma16(src, &xs[(r * 260 + 2 + g * 16) * 32]);
      }
    }
    __syncthreads();  // DMA drained (vmcnt(0) before barrier)
#pragma unroll 1
    for (int tap = 0; tap < 9; ++tap) {
      bf16x8 aCur[4];
#pragma unroll
      for (int mt = 0; mt < 4; ++mt) aCur[mt] = aNxt[mt];
      {  // prefetch next slab's A fragments (q*9+tap+1); last one reads harmless ws bytes
        int p = q * 9 + tap + 1;
        const u16* pp = wt2 + p * 4096 + aoff;
#pragma unroll
        for (int mt = 0; mt < 4; ++mt) aNxt[mt] = *reinterpret_cast<const bf16x8*>(pp + mt * 512);
      }
      const int ky = tap / 3, kx = tap - ky * 3;
      const u16* sp0 = &xs[(ky * 260 + kx + 1) * 32 + ldsLaneOff];
      bf16x8 bb[8];
#pragma unroll
      for (int nt = 0; nt < 8; ++nt)
        bb[nt] = *reinterpret_cast<const bf16x8*>(sp0 + nt * 512);
#pragma unroll
      for (int mt = 0; mt < 4; ++mt)
#pragma unroll
        for (int nt = 0; nt < 8; ++nt)
          acc[mt][nt] =
              __builtin_amdgcn_mfma_f32_16x16x32_bf16(aCur[mt], bb[nt], acc[mt][nt], 0, 0, 0);
    }
  }
  // epilogue: BN fold, write f32 f, fused 1x1 att dot
  const bool brA = (wave < 2);
  const float* wsel = brA ? wA66 : wB66;
  const long ob = (long)b * (128 * 65536) + h * 256;
  float pa[8];
#pragma unroll
  for (int nt = 0; nt < 8; ++nt) pa[nt] = 0.f;
#pragma unroll
  for (int mt = 0; mt < 4; ++mt) {
    int cob = mbase + mt * 16 + quad * 4;
    f32x4 scl = *reinterpret_cast<const f32x4*>(scale + cob);
    f32x4 shf = *reinterpret_cast<const f32x4*>(shift + cob);
    float wv[4];
#pragma unroll
    for (int e = 0; e < 4; ++e) wv[e] = wsel[mt * 16 + quad * 4 + e];
#pragma unroll
    for (int nt = 0; nt < 8; ++nt) {
      int wo = nbase + nt * 16 + l15;
#pragma unroll
      for (int e = 0; e < 4; ++e) {
        float v = acc[mt][nt][e] * scl[e] + shf[e];
        f[ob + (long)(cob + e) * 65536 + wo] = v;
        pa[nt] += wv[e] * v;
      }
    }
  }
#pragma unroll
  for (int nt = 0; nt < 8; ++nt) {
    pa[nt] += __shfl_xor(pa[nt], 16);
    pa[nt] += __shfl_xor(pa[nt], 32);
  }
  float w64 = wsel[64], w65 = wsel[65];
  float sc = brA ? attc[0] : attc[2];
  float sh = brA ? attc[1] : attc[3];
  float ghv = fabsf((float)h - 127.5f) * (1.f / 128.f);
  float* ap = brA ? atta : attb;
#pragma unroll
  for (int j = 0; j < 2; ++j) {
    int nt = quad * 2 + j;
    int col = nbase + nt * 16 + l15;
    float gwv = fabsf((float)col - 127.5f) * (1.f / 128.f);
    ap[b * 65536 + h * 256 + col] = (pa[nt] + w64 * ghv + w65 * gwv) * sc + sh;
  }
}

// ---------------- map: 3x3 conv over [att, gh, gw, pr] + sigmoid, in-place mul ----------------
__global__ void map_kernel(const float* __restrict__ atta, const float* __restrict__ attb,
                           const float* __restrict__ awA, const float* __restrict__ awB,
                           const float* __restrict__ s1p, const float* __restrict__ s2p,
                           float* __restrict__ out) {
  __shared__ float wsh[72];
  __shared__ float la[3 * 258], lb[3 * 258];
  int tid = threadIdx.x;
  int bid = blockIdx.x;
  int h = bid & 255, b = bid >> 8;
  if (tid < 36) wsh[tid] = awA[tid];
  else if (tid < 72) wsh[tid] = awB[tid - 36];
  for (int i = tid; i < 774; i += 256) {
    int r = i / 258, cc = i - r * 258;
    int ww = cc - 1, hh = h + r - 1;
    float va = 0.f, vb = 0.f;
    if ((unsigned)hh < 256u && (unsigned)ww < 256u) {
      int o = b * 65536 + hh * 256 + ww;
      va = atta[o];
      vb = attb[o];
    }
    la[r * 258 + cc] = va;
    lb[r * 258 + cc] = vb;
  }
  __syncthreads();
  const float r2 = sqrtf(2.f);
  const float rmx = r2 * (127.5f / 128.f);
  const float rmn = r2 * (0.5f / 128.f);
  const float Kc = 2.f / (rmx - rmn);
  const float C0 = 1.f - rmx * Kc;
  int w = tid;
  float suma = 0.f, sumb = 0.f;
#pragma unroll
  for (int ky = 0; ky < 3; ++ky) {
    int hh = h + ky - 1;
    if ((unsigned)hh < 256u) {
      float ghv = fabsf((float)hh - 127.5f) * (1.f / 128.f);
#pragma unroll
      for (int kx = 0; kx < 3; ++kx) {
        int ww = w + kx - 1;
        if ((unsigned)ww < 256u) {
          int t = ky * 3 + kx;
          float gwv = fabsf((float)ww - 127.5f) * (1.f / 128.f);
          float prv = Kc * sqrtf(ghv * ghv + gwv * gwv) + C0;
          suma += wsh[t] * la[ky * 258 + ww + 1] + wsh[9 + t] * ghv + wsh[18 + t] * gwv +
                  wsh[27 + t] * prv;
          sumb += wsh[36 + t] * lb[ky * 258 + ww + 1] + wsh[45 + t] * ghv + wsh[54 + t] * gwv +
                  wsh[63 + t] * prv;
        }
      }
    }
  }
  float mfa = s1p[0] / (1.f + expf(-suma));
  float mfb = s2p[0] / (1.f + expf(-sumb));
  long base = (long)b * (128 * 65536) + h * 256 + w;
#pragma unroll 4
  for (int co = 0; co < 64; ++co) {
    long o = base + (long)co * 65536;
    out[o] = out[o] * mfa;
  }
#pragma unroll 4
  for (int co = 64; co < 128; ++co) {
    long o = base + (long)co * 65536;
    out[o] = out[o] * mfb;
  }
}

// ================= fallback path (round-2, known-good) =================
__global__ void prep0_kernel(const float* __restrict__ cwA, const float* __restrict__ cbA,
                             const float* __restrict__ cwB, const float* __restrict__ cbB,
                             const float* gA, const float* beA, const float* mA, const float* vA,
                             const float* gB, const float* beB, const float* mB, const float* vB,
                             const float* abA, const float* abB,
                             const float* agA, const float* abeA, const float* amA, const float* avA,
                             const float* agB, const float* abeB, const float* amB, const float* avB,
                             u16* __restrict__ wt, float* __restrict__ scale,
                             float* __restrict__ shift, float* __restrict__ attc) {
  int g = blockIdx.x * 256 + threadIdx.x;
  if (g < 147456) {
    int cin = g & 127, co = (g >> 7) & 127, tap = g >> 14;
    float v = (co < 64) ? cwA[(co * 128 + cin) * 9 + tap]
                        : cwB[((co - 64) * 128 + cin) * 9 + tap];
    wt[g] = f2bf(v);
  }
  if (g < 128) {
    bool a = g < 64;
    int c = a ? g : g - 64;
    float sc = (a ? gA[c] : gB[c]) / sqrtf((a ? vA[c] : vB[c]) + 1e-3f);
    scale[g] = sc;
    shift[g] = ((a ? cbA[c] : cbB[c]) - (a ? mA[c] : mB[c])) * sc + (a ? beA[c] : beB[c]);
  }
  if (g == 0) {
    float scA = agA[0] / sqrtf(avA[0] + 1e-5f);
    float scB = agB[0] / sqrtf(avB[0] + 1e-5f);
    attc[0] = scA;
    attc[1] = (abA[0] - amA[0]) * scA + abeA[0];
    attc[2] = scB;
    attc[3] = (abB[0] - amB[0]) * scB + abeB[0];
  }
}

#define LPAD 36
__global__ __launch_bounds__(256, 2) void conv0_kernel(
    const float* __restrict__ x, const u16* __restrict__ wt,
    const float* __restrict__ scale, const float* __restrict__ shift,
    const float* __restrict__ attc, const float* __restrict__ wA66,
    const float* __restrict__ wB66, float* __restrict__ f,
    float* __restrict__ atta, float* __restrict__ attb) {
  __shared__ u16 xs[3 * 260 * LPAD];
  const int tid = threadIdx.x;
  const int bid = blockIdx.x;
  const int h = (bid & 7) * 32 + ((bid >> 3) & 31);
  const int b = bid >> 8;
  const int l15 = tid & 15, quad = (tid >> 4) & 3, wave = tid >> 6;
  const int mbase = (wave >> 1) * 64;
  const int nbase = (wave & 1) * 128;
  f32x4 acc[4][8];
  const f32x4 z = {0.f, 0.f, 0.f, 0.f};
#pragma unroll
  for (int i = 0; i < 4; ++i)
#pragma unroll
    for (int j = 0; j < 8; ++j) acc[i][j] = z;
  const u16* wbase = wt + (mbase + l15) * 128 + quad * 8;
  const long xb = (long)b * (128 * 65536);
  bf16x8 aNxt[4];
  for (int q = 0; q < 4; ++q) {
    {
      const u16* p = wbase + q * 32;
#pragma unroll
      for (int mt = 0; mt < 4; ++mt) aNxt[mt] = *reinterpret_cast<const bf16x8*>(p + mt * 2048);
    }
    __syncthreads();
    for (int i = tid; i < 12480; i += 256) {
      int p = i % 130;
      int rest = i / 130;
      int c = rest & 31, r = rest >> 5;
      int w = p * 2 - 2;
      int hh = h + r - 1;
      float2 v = make_float2(0.f, 0.f);
      if ((unsigned)hh < 256u && (unsigned)w < 256u)
        v = *reinterpret_cast<const float2*>(x + xb + (long)(q * 32 + c) * 65536 + hh * 256 + w);
      int dst = (r * 260 + p * 2) * LPAD + c;
      xs[dst] = f2bf(v.x);
      xs[dst + LPAD] = f2bf(v.y);
    }
    __syncthreads();
#pragma unroll 1
    for (int tap = 0; tap < 9; ++tap) {
      bf16x8 aCur[4];
#pragma unroll
      for (int mt = 0; mt < 4; ++mt) aCur[mt] = aNxt[mt];
      if (tap < 8) {
        const u16* p = wbase + q * 32 + (tap + 1) * 16384;
#pragma unroll
        for (int mt = 0; mt < 4; ++mt) aNxt[mt] = *reinterpret_cast<const bf16x8*>(p + mt * 2048);
      }
      const int ky = tap / 3, kx = tap - ky * 3;
      bf16x8 bb[8];
#pragma unroll
      for (int nt = 0; nt < 8; ++nt) {
        int col = nbase + nt * 16 + l15 + kx + 1;
        const u16* sp = &xs[(ky * 260 + col) * LPAD + quad * 8];
        uint2 lo = *reinterpret_cast<const uint2*>(sp);
        uint2 hi = *reinterpret_cast<const uint2*>(sp + 4);
        uint4v u;
        u[0] = lo.x; u[1] = lo.y; u[2] = hi.x; u[3] = hi.y;
        bb[nt] = __builtin_bit_cast(bf16x8, u);
      }
#pragma unroll
      for (int mt = 0; mt < 4; ++mt)
#pragma unroll
        for (int nt = 0; nt < 8; ++nt)
          acc[mt][nt] =
              __builtin_amdgcn_mfma_f32_16x16x32_bf16(aCur[mt], bb[nt], acc[mt][nt], 0, 0, 0);
    }
  }
  const bool brA = (wave < 2);
  const float* wsel = brA ? wA66 : wB66;
  const long ob = (long)b * (128 * 65536) + h * 256;
  float pa[8];
#pragma unroll
  for (int nt = 0; nt < 8; ++nt) pa[nt] = 0.f;
#pragma unroll
  for (int mt = 0; mt < 4; ++mt) {
    int cob = mbase + mt * 16 + quad * 4;
    f32x4 scl = *reinterpret_cast<const f32x4*>(scale + cob);
    f32x4 shf = *reinterpret_cast<const f32x4*>(shift + cob);
    float wv[4];
#pragma unroll
    for (int e = 0; e < 4; ++e) wv[e] = wsel[mt * 16 + quad * 4 + e];
#pragma unroll
    for (int nt = 0; nt < 8; ++nt) {
      int wo = nbase + nt * 16 + l15;
#pragma unroll
      for (int e = 0; e < 4; ++e) {
        float v = acc[mt][nt][e] * scl[e] + shf[e];
        f[ob + (long)(cob + e) * 65536 + wo] = v;
        pa[nt] += wv[e] * v;
      }
    }
  }
#pragma unroll
  for (int nt = 0; nt < 8; ++nt) {
    pa[nt] += __shfl_xor(pa[nt], 16);
    pa[nt] += __shfl_xor(pa[nt], 32);
  }
  float w64 = wsel[64], w65 = wsel[65];
  float sc = brA ? attc[0] : attc[2];
  float sh = brA ? attc[1] : attc[3];
  float ghv = fabsf((float)h - 127.5f) * (1.f / 128.f);
  float* ap = brA ? atta : attb;
#pragma unroll
  for (int j = 0; j < 2; ++j) {
    int nt = quad * 2 + j;
    int col = nbase + nt * 16 + l15;
    float gwv = fabsf((float)col - 127.5f) * (1.f / 128.f);
    ap[b * 65536 + h * 256 + col] = (pa[nt] + w64 * ghv + w65 * gwv) * sc + sh;
  }
}

extern "C" void kernel_launch(void* const* d_in, const int* in_sizes, int n_in,
                              void* d_out, int out_size, void* d_ws, size_t ws_size,
                              hipStream_t stream) {
  const float* x = (const float*)d_in[0];
  u16* wt = (u16*)d_ws;                                    // 294912 B
  float* scale = (float*)((char*)d_ws + 294912);           // 512 B
  float* shift = (float*)((char*)d_ws + 295424);           // 512 B
  float* attc = (float*)((char*)d_ws + 295936);            // 64 B
  float* atta = (float*)((char*)d_ws + 296000);            // 1 MiB
  float* attb = (float*)((char*)d_ws + 296000 + 1048576);  // 1 MiB
  u16* xT = (u16*)((char*)d_ws + 2393344);                 // 67,108,864 B
  float* out = (float*)d_out;
  const size_t need = 2393344ull + 67108864ull;

  if (ws_size >= need) {
    xpose_kernel<<<4096, 256, 0, stream>>>(x, xT);
    prep_kernel<<<576, 256, 0, stream>>>(
        (const float*)d_in[1], (const float*)d_in[2], (const float*)d_in[3], (const float*)d_in[4],
        (const float*)d_in[5], (const float*)d_in[6], (const float*)d_in[7], (const float*)d_in[8],
        (const float*)d_in[9], (const float*)d_in[10], (const float*)d_in[11], (const float*)d_in[12],
        (const float*)d_in[14], (const float*)d_in[16],
        (const float*)d_in[17], (const float*)d_in[18], (const float*)d_in[19], (const float*)d_in[20],
        (const float*)d_in[21], (const float*)d_in[22], (const float*)d_in[23], (const float*)d_in[24],
        wt, scale, shift, attc);
    conv_kernel<<<1024, 256, 0, stream>>>(xT, wt, scale, shift, attc,
                                          (const float*)d_in[13], (const float*)d_in[15],
                                          out, atta, attb);
  } else {
    prep0_kernel<<<576, 256, 0, stream>>>(
        (const float*)d_in[1], (const float*)d_in[2], (const float*)d_in[3], (const float*)d_in[4],
        (const float*)d_in[5], (const float*)d_in[6], (const float*)d_in[7], (const float*)d_in[8],
        (const float*)d_in[9], (const float*)d_in[10], (const float*)d_in[11], (const float*)d_in[12],
        (const float*)d_in[14], (const float*)d_in[16],
        (const float*)d_in[17], (const float*)d_in[18], (const float*)d_in[19], (const float*)d_in[20],
        (const float*)d_in[21], (const float*)d_in[22], (const float*)d_in[23], (const float*)d_in[24],
        wt, scale, shift, attc);
    conv0_kernel<<<1024, 256, 0, stream>>>(x, wt, scale, shift, attc,
                                           (const float*)d_in[13], (const float*)d_in[15],
                                           out, atta, attb);
  }
  map_kernel<<<1024, 256, 0, stream>>>(atta, attb, (const float*)d_in[25], (const float*)d_in[26],
                                       (const float*)d_in[27], (const float*)d_in[28], out);
}